// Round 4
// baseline (77.462 us; speedup 1.0000x reference)
//
#include <hip/hip_runtime.h>

// NNLoss: bidirectional Chamfer NN-L1. B=16, N=M=2048, D=2, scalar f32 out.
//
// R4: same fused exact structure as R3 (segment-split scan -> packed u64
// candidates in LDS -> u64-min merge = exact jnp.argmin first-index), plus:
//  - QPT=8 queries/thread (8 independent select chains: latency hiding)
//  - v_pk_fma_f32 packed distances (v2f + __builtin_elementwise_fma)
//  - pairwise pre-select (2 points -> 1 best-update on the carried chain)
//  - BLK=512, 512 blocks -> 2 blocks/CU (phases overlap across blocks)
//  - SoA db in LDS, per-segment pad (stride 68) -> conflict-free scan reads
// Harness floor: ~40 us d_ws poison-fill + ~9 us restores (not controllable).

typedef float v2f __attribute__((ext_vector_type(2)));

constexpr int B      = 16;
constexpr int NPTS   = 2048;
constexpr int BLK    = 512;
constexpr int G      = 128;            // queries per block
constexpr int QPT    = 8;              // queries per thread
constexpr int QG     = G / QPT;        // 16 threads per segment group
constexpr int S      = BLK / QG;       // 32 db segments
constexpr int SEGLEN = NPTS / S;       // 64 points per segment
constexpr int ITERS  = SEGLEN / 2;     // 32 packed iters
constexpr int SSTR   = SEGLEN + 4;     // 68: segs hit distinct banks, 8B-aligned
constexpr int NBLK   = 2 * B * (NPTS / G);  // 512 blocks -> 2 blocks/CU

__global__ __launch_bounds__(BLK, 4) void nn_main(
    const float* __restrict__ preds, const float* __restrict__ targs,
    const float* __restrict__ subcoef, float* __restrict__ ws_out)
{
    __shared__ float sx[S * SSTR];                 // 8.5 KB SoA db x (padded)
    __shared__ float sy[S * SSTR];                 // 8.5 KB SoA db y (padded)
    __shared__ unsigned long long cand[S * G];     // 32 KB candidates
    __shared__ float ssum[BLK / 64];

    const int blk  = blockIdx.x;
    const int dir  = blk >> 8;          // 0: preds->targs (subcoef), 1: reverse
    const int b    = (blk >> 4) & 15;
    const int tile = blk & 15;

    const float2* qb = reinterpret_cast<const float2*>(dir == 0 ? preds : targs)
                       + b * NPTS + tile * G;
    const float2* db = reinterpret_cast<const float2*>(dir == 0 ? targs : preds)
                       + b * NPTS;

    // Stage db batch as padded SoA (coalesced float2 global reads).
    for (int i = threadIdx.x; i < NPTS; i += BLK) {
        const float2 p = db[i];
        const int slot = (i >> 6) * SSTR + (i & 63);
        sx[slot] = p.x;
        sy[slot] = p.y;
    }

    const int qg  = threadIdx.x & (QG - 1);   // query sub-slot
    const int seg = threadIdx.x / QG;         // db segment for this thread

    // 8 register-resident queries: q coefficients splatted for packed fma.
    v2f   m2x[QPT], m2y[QPT];
    float best[QPT];
    int   bi[QPT];
    #pragma unroll
    for (int q = 0; q < QPT; ++q) {
        const float2 qp = qb[qg + q * QG];
        const float ax = -2.0f * qp.x, ay = -2.0f * qp.y;
        m2x[q] = {ax, ax};
        m2y[q] = {ay, ay};
        best[q] = 3.402823466e+38f;
        bi[q] = 0;
    }
    __syncthreads();

    // Scan segment. f(t) = t^2 - 2 q.t (monotone in d^2 per query; computed
    // bit-identically for a given q by every segment thread -> exact merge).
    const v2f* sxp = reinterpret_cast<const v2f*>(sx + seg * SSTR);
    const v2f* syp = reinterpret_cast<const v2f*>(sy + seg * SSTR);
    const int idxBase = seg * SEGLEN;
    #pragma unroll 4
    for (int i = 0; i < ITERS; ++i) {
        const v2f px = sxp[i];
        const v2f py = syp[i];
        const v2f t2 = __builtin_elementwise_fma(px, px, py * py);
        const int i0 = idxBase + 2 * i;
        #pragma unroll
        for (int q = 0; q < QPT; ++q) {
            const v2f d = __builtin_elementwise_fma(
                m2x[q], px, __builtin_elementwise_fma(m2y[q], py, t2));
            // Pairwise pre-select: strict < -> even (earlier) index wins ties.
            const bool lt = d.y < d.x;
            const float dm = lt ? d.y : d.x;
            const int   im = lt ? i0 + 1 : i0;
            // Carried chain: strict <, i0 ascending -> first index wins.
            if (dm < best[q]) { best[q] = dm; bi[q] = im; }
        }
    }

    // Publish packed candidates: monotone-ordered f bits high, index low.
    #pragma unroll
    for (int q = 0; q < QPT; ++q) {
        unsigned int fb = __float_as_uint(best[q]);
        fb ^= 0x80000000u | (unsigned int)((int)fb >> 31);  // total-order map
        cand[seg * G + qg + q * QG] =
            ((unsigned long long)fb << 32) | (unsigned int)bi[q];
    }
    __syncthreads();

    // First G threads: u64-min over 32 segment candidates = exact argmin.
    float val = 0.0f;
    if (threadIdx.x < G) {
        unsigned long long bp = cand[threadIdx.x];
        #pragma unroll
        for (int s = 1; s < S; ++s) {
            const unsigned long long v = cand[s * G + threadIdx.x];
            bp = v < bp ? v : bp;
        }
        const int idx = (int)(unsigned int)bp;
        const float2 qp = qb[threadIdx.x];
        const float2 tp = db[idx];            // L2-hot scattered 8B load
        float sxc = 1.0f, syc = 1.0f;
        if (dir == 0) { sxc = subcoef[0]; syc = subcoef[1]; }
        val = fabsf(qp.x - tp.x) * sxc + fabsf(qp.y - tp.y) * syc;
    }

    // Block reduction (all threads; inactive hold 0).
    #pragma unroll
    for (int off = 32; off > 0; off >>= 1)
        val += __shfl_down(val, off, 64);
    if ((threadIdx.x & 63) == 0) ssum[threadIdx.x >> 6] = val;
    __syncthreads();
    if (threadIdx.x == 0) {
        float s = ssum[0];
        #pragma unroll
        for (int w = 1; w < BLK / 64; ++w) s += ssum[w];
        ws_out[blk] = s;   // deterministic, no atomics, no init needed
    }
}

__global__ __launch_bounds__(NBLK) void nn_reduce(
    const float* __restrict__ ws_in, float* __restrict__ out)
{
    __shared__ float ssum[NBLK / 64];
    float val = ws_in[threadIdx.x];
    #pragma unroll
    for (int off = 32; off > 0; off >>= 1)
        val += __shfl_down(val, off, 64);
    if ((threadIdx.x & 63) == 0) ssum[threadIdx.x >> 6] = val;
    __syncthreads();
    if (threadIdx.x == 0) {
        float s = ssum[0];
        #pragma unroll
        for (int w = 1; w < NBLK / 64; ++w) s += ssum[w];
        out[0] = s;
    }
}

extern "C" void kernel_launch(void* const* d_in, const int* in_sizes, int n_in,
                              void* d_out, int out_size, void* d_ws, size_t ws_size,
                              hipStream_t stream) {
    const float* preds   = (const float*)d_in[0];
    const float* targs   = (const float*)d_in[1];
    const float* subcoef = (const float*)d_in[2];
    float* out = (float*)d_out;
    float* ws  = (float*)d_ws;

    nn_main<<<NBLK, BLK, 0, stream>>>(preds, targs, subcoef, ws);
    nn_reduce<<<1, NBLK, 0, stream>>>(ws, out);
}